// Round 2
// baseline (335.714 us; speedup 1.0000x reference)
//
#include <hip/hip_runtime.h>
#include <math.h>

#define N_REAL 2800
#define NPAD   3000
#define F_IN   8192
#define H1     256
#define H2     128
#define NE     179200
#define UDIM   512
#define NGATE  512
#define MPAD   3072
#define SPLITK 16
#define KCH    (F_IN / SPLITK)   // 512
#define NHB    8                 // privatized hist/scatter blocks
#define EPB    (NE / NHB)        // 22400

typedef _Float16 half8_t __attribute__((ext_vector_type(8)));
typedef _Float16 half4_t __attribute__((ext_vector_type(4)));
typedef float    floatx4 __attribute__((ext_vector_type(4)));

typedef _Float16 AsT[64][8];    // [8][64][8]  = 8 KB
typedef _Float16 BsT[256][8];   // [8][256][8] = 32 KB

__device__ __forceinline__ void async_g2l_16(const _Float16* g, _Float16* l) {
    __builtin_amdgcn_global_load_lds(
        (const __attribute__((address_space(1))) unsigned int*)g,
        (__attribute__((address_space(3))) unsigned int*)l, 16, 0, 0);
}

// ---------------- prep: fc0_w -> wTp | Wcp + biasv | h0 -> U16 copy ----------------------------
__global__ __launch_bounds__(256)
void prep_kernel(const float* __restrict__ w, const float* __restrict__ Wx,
                 const float* __restrict__ cw0, const float* __restrict__ cw1,
                 const float* __restrict__ bg, const float* __restrict__ cb,
                 const float* __restrict__ h0,
                 _Float16* __restrict__ wTp, _Float16* __restrict__ Wcp,
                 float* __restrict__ biasv, _Float16* __restrict__ U16) {
    int b = blockIdx.x;
    if (b < 2048) {
        __shared__ float tile[32][33];
        int k0 = (b & 255) * 32;
        int n0 = (b >> 8) * 32;
        int tx = threadIdx.x & 31, ty = threadIdx.x >> 5; // 32 x 8
#pragma unroll
        for (int r = 0; r < 4; r++)
            tile[ty + r * 8][tx] = w[(size_t)(k0 + ty + r * 8) * H1 + n0 + tx];
        __syncthreads();
        int t = threadIdx.x;
        if (t < 128) {
            int u_l = t >> 5;
            int n_l = t & 31;
            half8_t h;
#pragma unroll
            for (int j = 0; j < 8; j++) h[j] = (_Float16)tile[u_l * 8 + j][n_l];
            *(half8_t*)&wTp[(((size_t)(k0 >> 3) + u_l) * H1 + n0 + n_l) * 8] = h;
        }
    } else if (b < 3072) {
        int idx = (b - 2048) * 256 + threadIdx.x;
        if (idx < UDIM * NGATE) {
            int col = idx >> 9;
            int f   = idx & 511;
            int g = col >> 7, o = col & 127;
            float v;
            if (f < H1)            v = Wx[((size_t)g * H1 + f) * H2 + o];
            else if (f < H1 + H2)  v = cw0[((size_t)g * H2 + (f - H1)) * H2 + o];
            else                   v = cw1[((size_t)g * H2 + (f - H1 - H2)) * H2 + o];
            Wcp[(((size_t)(f >> 3)) * NGATE + col) * 8 + (f & 7)] = (_Float16)v;
            if (f == 0) biasv[col] = bg[col] + cb[col];
        }
    } else {
        int q = (b - 3072) * 256 + threadIdx.x;   // 0..98303
        int m = q >> 5;
        int o4 = (q & 31) * 4;
        half4_t h = {};
        if (m < NPAD) {
            float4 v = *(const float4*)&h0[(size_t)m * H2 + o4];
            h[0] = (_Float16)v.x; h[1] = (_Float16)v.y; h[2] = (_Float16)v.z; h[3] = (_Float16)v.w;
        }
        *(half4_t*)&U16[(size_t)m * UDIM + H1 + o4] = h;
    }
}

// ---------------- fused: privatized hist (8 LDS blocks) || GEMM1 ------------------------------
// hist: per-block LDS histogram (no global atomics) -> partial arrays cnt_p/deg_p.
// gemm blocks: sk = lin%16 -> each k-chunk of wTp pinned to one XCD (L2-resident).
__global__ __launch_bounds__(256, 3)
void g1hist_kernel(const float* __restrict__ x, const _Float16* __restrict__ wTp,
                   const int* __restrict__ ei, const float* __restrict__ ew,
                   float* __restrict__ P, int* __restrict__ cnt_p,
                   float* __restrict__ deg_p) {
    __shared__ __align__(16) char smem[40960];
    const int b = blockIdx.x;
    const int t = threadIdx.x;
    if (b < NHB) {
        float* sdeg = (float*)smem;            // 12 KB
        int*   scnt = (int*)(smem + 12288);    // 12 KB
        for (int i = t; i < 3072; i += 256) { sdeg[i] = 0.f; scnt[i] = 0; }
        __syncthreads();
        int e0 = b * EPB;
        for (int i = t; i < EPB; i += 256) {
            int e = e0 + i;
            atomicAdd(&sdeg[ei[e]], ew[e]);
            atomicAdd(&scnt[ei[NE + e]], 1);
        }
        __syncthreads();
        for (int i = t; i < 3072; i += 256) {
            deg_p[b * 3072 + i] = sdeg[i];
            cnt_p[b * 3072 + i] = scnt[i];
        }
        return;
    }
    AsT* As = reinterpret_cast<AsT*>(smem);            // [8][64][8]
    BsT* Bs = reinterpret_cast<BsT*>(smem + 8192);     // [8][256][8]
    const int lin = b - NHB;
    const int sk  = lin & 15;
    const int mb  = lin >> 4;
    const int wave = t >> 6, lane = t & 63;
    const int l16 = lane & 15, u4 = lane >> 4;
    const int m0 = mb * 64;
    const int kbase = sk * KCH;

    const int arow = t >> 2;
    const int aseg = t & 3;
    const bool avalid = (m0 + arow) < N_REAL;
    const float* agp = x + (size_t)(m0 + arow) * F_IN + kbase + aseg * 16;

    floatx4 acc[4][4] = {};

    float4 a0 = make_float4(0.f, 0.f, 0.f, 0.f), a1 = a0, a2 = a0, a3 = a0;
    if (avalid) {
        a0 = *(const float4*)(agp + 0);
        a1 = *(const float4*)(agp + 4);
        a2 = *(const float4*)(agp + 8);
        a3 = *(const float4*)(agp + 12);
    }

    for (int kk = 0; kk < KCH; kk += 64) {
        const _Float16* bbase = wTp + ((size_t)((kbase + kk) >> 3)) * (H1 * 8);
#pragma unroll
        for (int q = 0; q < 2; q++) {
            int u = wave * 2 + q;
#pragma unroll
            for (int rg = 0; rg < 4; rg++)
                async_g2l_16(bbase + ((size_t)u * H1 + rg * 64 + lane) * 8,
                             &Bs[u][rg * 64 + lane][0]);
        }
        half8_t hlo, hhi;
        hlo[0] = (_Float16)a0.x; hlo[1] = (_Float16)a0.y; hlo[2] = (_Float16)a0.z; hlo[3] = (_Float16)a0.w;
        hlo[4] = (_Float16)a1.x; hlo[5] = (_Float16)a1.y; hlo[6] = (_Float16)a1.z; hlo[7] = (_Float16)a1.w;
        hhi[0] = (_Float16)a2.x; hhi[1] = (_Float16)a2.y; hhi[2] = (_Float16)a2.z; hhi[3] = (_Float16)a2.w;
        hhi[4] = (_Float16)a3.x; hhi[5] = (_Float16)a3.y; hhi[6] = (_Float16)a3.z; hhi[7] = (_Float16)a3.w;
        *(half8_t*)&As[aseg * 2][arow][0]     = hlo;
        *(half8_t*)&As[aseg * 2 + 1][arow][0] = hhi;
        __syncthreads();
        if (kk + 64 < KCH && avalid) {
            a0 = *(const float4*)(agp + kk + 64);
            a1 = *(const float4*)(agp + kk + 68);
            a2 = *(const float4*)(agp + kk + 72);
            a3 = *(const float4*)(agp + kk + 76);
        }
#pragma unroll
        for (int ks = 0; ks < 2; ks++) {
            half8_t a[4], bfr[4];
#pragma unroll
            for (int i = 0; i < 4; i++) a[i] = *(const half8_t*)&As[ks * 4 + u4][i * 16 + l16][0];
#pragma unroll
            for (int j = 0; j < 4; j++) bfr[j] = *(const half8_t*)&Bs[ks * 4 + u4][wave * 64 + j * 16 + l16][0];
#pragma unroll
            for (int i = 0; i < 4; i++)
#pragma unroll
                for (int j = 0; j < 4; j++)
                    acc[i][j] = __builtin_amdgcn_mfma_f32_16x16x32_f16(a[i], bfr[j], acc[i][j], 0, 0, 0);
        }
        __syncthreads();
    }

    float* Pb = P + ((size_t)sk * MPAD + m0) * H1;
#pragma unroll
    for (int i = 0; i < 4; i++)
#pragma unroll
        for (int j = 0; j < 4; j++) {
            int n = wave * 64 + j * 16 + l16;
#pragma unroll
            for (int r = 0; r < 4; r++)
                Pb[(size_t)(i * 16 + u4 * 4 + r) * H1 + n] = acc[i][j][r];
        }
}

// ---------------- shared zreduce body: P slices -> relu -> U16 z slice (256 thr) ---------------
__device__ __forceinline__ void zreduce_body(int zb, int t, const float* __restrict__ P,
                                             const float* __restrict__ fc0_b,
                                             _Float16* __restrict__ U16) {
    int q = zb * 256 + t;
    int m = q >> 6;
    int n4 = (q & 63) * 4;
    float s0 = 0.f, s1 = 0.f, s2 = 0.f, s3 = 0.f;
#pragma unroll
    for (int sk = 0; sk < SPLITK; sk++) {
        float4 p = *(const float4*)&P[((size_t)sk * MPAD + m) * H1 + n4];
        s0 += p.x; s1 += p.y; s2 += p.z; s3 += p.w;
    }
    float4 bb = *(const float4*)&fc0_b[n4];
    half4_t h;
    h[0] = (_Float16)fmaxf(s0 + bb.x, 0.f);
    h[1] = (_Float16)fmaxf(s1 + bb.y, 0.f);
    h[2] = (_Float16)fmaxf(s2 + bb.z, 0.f);
    h[3] = (_Float16)fmaxf(s3 + bb.w, 0.f);
    *(half4_t*)&U16[(size_t)m * UDIM + n4] = h;
}

// ---------------- fused: scan (merge partials, 1 block) || zreduce first half ------------------
__global__ __launch_bounds__(256)
void scanz_kernel(const int* __restrict__ cnt_p, const float* __restrict__ deg_p,
                  int* __restrict__ offsets, float* __restrict__ dinv,
                  const float* __restrict__ P, const float* __restrict__ fc0_b,
                  _Float16* __restrict__ U16) {
    int b = blockIdx.x;
    int t = threadIdx.x;
    if (b == 0) {
        __shared__ int wt[4];
        int i0 = t * 12;
        int v[12];
        int s = 0;
#pragma unroll
        for (int j = 0; j < 12; j++) {
            int tv = 0;
#pragma unroll
            for (int bb = 0; bb < NHB; bb++) tv += cnt_p[bb * 3072 + i0 + j];
            v[j] = tv; s += tv;
        }
        int incl = s;
#pragma unroll
        for (int d = 1; d < 64; d <<= 1) {
            int n = __shfl_up(incl, d);
            if ((t & 63) >= d) incl += n;
        }
        if ((t & 63) == 63) wt[t >> 6] = incl;
        __syncthreads();
        int wbase = 0;
#pragma unroll
        for (int w = 0; w < 4; w++) wbase += (w < (t >> 6)) ? wt[w] : 0;
        int run = wbase + incl - s;
#pragma unroll
        for (int j = 0; j < 12; j++) { offsets[i0 + j] = run; run += v[j]; }
        for (int i = t; i < NPAD; i += 256) {
            float d = 0.f;
#pragma unroll
            for (int bb = 0; bb < NHB; bb++) d += deg_p[bb * 3072 + i];
            dinv[i] = (d > 0.f) ? rsqrtf(d) : 0.f;
        }
    } else {
        zreduce_body(b - 1, t, P, fc0_b, U16);      // zb 0..383
    }
}

// ---------------- fused: privatized scatter (8 LDS blocks) || zreduce second half --------------
__global__ __launch_bounds__(256)
void scatz_kernel(const int* __restrict__ ei, const int* __restrict__ offsets,
                  const int* __restrict__ cnt_p, int* __restrict__ eid,
                  const float* __restrict__ P, const float* __restrict__ fc0_b,
                  _Float16* __restrict__ U16) {
    int b = blockIdx.x;
    int t = threadIdx.x;
    if (b < NHB) {
        __shared__ int sbase[3072];
        for (int j = t; j < 3072; j += 256) {
            int a = offsets[j];
            for (int bb = 0; bb < b; bb++) a += cnt_p[bb * 3072 + j];
            sbase[j] = a;
        }
        __syncthreads();
        int e0 = b * EPB;
        for (int i = t; i < EPB; i += 256) {
            int e = e0 + i;
            int c = ei[NE + e];
            int p = atomicAdd(&sbase[c], 1);
            eid[p] = e;
        }
    } else {
        zreduce_body(384 + (b - NHB), t, P, fc0_b, U16);  // zb 384..767
    }
}

// ---------------- gemm2 body: gates_part[m,n] += U16[:,k0:kend] @ Wcp slice --------------------
__device__ __forceinline__ void gemm2_body(const _Float16* __restrict__ U16,
                                           const _Float16* __restrict__ Wcp,
                                           float* __restrict__ g,
                                           int k0, int kend, int blk, int t, char* smem) {
    AsT* As = reinterpret_cast<AsT*>(smem);
    BsT* Bs = reinterpret_cast<BsT*>(smem + 8192);
    const int wave = t >> 6, lane = t & 63;
    const int l16 = lane & 15, u4 = lane >> 4;
    const int n0 = (blk & 1) * 256;
    const int m0 = (blk >> 1) * 64;

    floatx4 acc[4][4] = {};

    for (int kk = k0; kk < kend; kk += 64) {
        const _Float16* bbase = Wcp + ((size_t)(kk >> 3)) * (NGATE * 8);
#pragma unroll
        for (int q = 0; q < 2; q++) {
            int u = wave * 2 + q;
            async_g2l_16(U16 + (size_t)(m0 + lane) * UDIM + kk + u * 8, &As[u][lane][0]);
#pragma unroll
            for (int rg = 0; rg < 4; rg++)
                async_g2l_16(bbase + ((size_t)u * NGATE + n0 + rg * 64 + lane) * 8,
                             &Bs[u][rg * 64 + lane][0]);
        }
        __syncthreads();
#pragma unroll
        for (int ks = 0; ks < 2; ks++) {
            half8_t a[4], bfr[4];
#pragma unroll
            for (int i = 0; i < 4; i++) a[i] = *(const half8_t*)&As[ks * 4 + u4][i * 16 + l16][0];
#pragma unroll
            for (int j = 0; j < 4; j++) bfr[j] = *(const half8_t*)&Bs[ks * 4 + u4][wave * 64 + j * 16 + l16][0];
#pragma unroll
            for (int i = 0; i < 4; i++)
#pragma unroll
                for (int j = 0; j < 4; j++)
                    acc[i][j] = __builtin_amdgcn_mfma_f32_16x16x32_f16(a[i], bfr[j], acc[i][j], 0, 0, 0);
        }
        __syncthreads();
    }

#pragma unroll
    for (int i = 0; i < 4; i++)
#pragma unroll
        for (int j = 0; j < 4; j++) {
            int n = n0 + wave * 64 + j * 16 + l16;
#pragma unroll
            for (int r = 0; r < 4; r++)
                g[(size_t)(m0 + i * 16 + u4 * 4 + r) * NGATE + n] = acc[i][j][r];
        }
}

// ---------------- fused: gemm2 part A (K 0..384: z+h0, no graph dep) || T1 gather --------------
__global__ __launch_bounds__(256, 3)
void g2gather_kernel(const _Float16* __restrict__ U16f, _Float16* __restrict__ U16,
                     const _Float16* __restrict__ Wcp, float* __restrict__ gates,
                     const int* __restrict__ ei, const float* __restrict__ ew,
                     const float* __restrict__ h0, const float* __restrict__ dinv,
                     const int* __restrict__ offsets, const int* __restrict__ eid) {
    __shared__ __align__(16) char smem[40960];
    int b = blockIdx.x;
    int t = threadIdx.x;
    if (b < 96) {
        gemm2_body(U16f, Wcp, gates, 0, 384, b, t, smem);
        return;
    }
    int*   sr = (int*)smem;              // 256 ints
    float* sw = (float*)(smem + 1024);   // 256 floats
    float* sa = (float*)(smem + 2048);   // 256 floats
    int n = b - 96;
    int o = t & 127;
    int g = t >> 7;
    int beg = offsets[n], end = offsets[n + 1];
    float dc = dinv[n];
    float acc = 0.f;
    for (int base = beg; base < end; base += 256) {
        int j = base + t;
        if (j < end) {
            int e = eid[j];
            int r = ei[e];
            sr[t] = r;
            sw[t] = -dinv[r] * ew[e];
        }
        __syncthreads();
        int cnt = min(256, end - base);
        int lo = g * 128;
        int hi = min(cnt, lo + 128);
        int k = lo;
        for (; k + 8 <= hi; k += 8) {
            int   r0 = sr[k],   r1 = sr[k+1], r2 = sr[k+2], r3 = sr[k+3];
            int   r4 = sr[k+4], r5 = sr[k+5], r6 = sr[k+6], r7 = sr[k+7];
            float w0 = sw[k],   w1 = sw[k+1], w2 = sw[k+2], w3 = sw[k+3];
            float w4 = sw[k+4], w5 = sw[k+5], w6 = sw[k+6], w7 = sw[k+7];
            float v0 = h0[(size_t)r0 * H2 + o];
            float v1 = h0[(size_t)r1 * H2 + o];
            float v2 = h0[(size_t)r2 * H2 + o];
            float v3 = h0[(size_t)r3 * H2 + o];
            float v4 = h0[(size_t)r4 * H2 + o];
            float v5 = h0[(size_t)r5 * H2 + o];
            float v6 = h0[(size_t)r6 * H2 + o];
            float v7 = h0[(size_t)r7 * H2 + o];
            acc += w0 * v0 + w1 * v1 + w2 * v2 + w3 * v3
                 + w4 * v4 + w5 * v5 + w6 * v6 + w7 * v7;
        }
        for (; k < hi; k++)
            acc += sw[k] * h0[(size_t)sr[k] * H2 + o];
        __syncthreads();
    }
    sa[t] = acc;
    __syncthreads();
    if (g == 0)
        U16[(size_t)n * UDIM + H1 + H2 + o] = (_Float16)((acc + sa[t + 128]) * dc);
}

// ---------------- gemm2 part B (K 384..512: T1 slice only) -------------------------------------
__global__ __launch_bounds__(256, 3)
void gemm2b_kernel(const _Float16* __restrict__ U16, const _Float16* __restrict__ Wcp,
                   float* __restrict__ gates) {
    __shared__ __align__(16) char smem[40960];
    gemm2_body(U16, Wcp, gates + (size_t)MPAD * NGATE, 384, 512, blockIdx.x, threadIdx.x, smem);
}

// ---------------- LSTM elementwise + bias + output projection ----------------------------------
__global__ __launch_bounds__(128)
void lstm_kernel(const float* __restrict__ gates, const float* __restrict__ c0,
                 const float* __restrict__ biasv, const float* __restrict__ fc_w,
                 const float* __restrict__ fc_b, float* __restrict__ out) {
    __shared__ float red[2];
    int n = blockIdx.x;
    int o = threadIdx.x;
    const float* g0 = gates + (size_t)n * NGATE;
    const float* g1 = g0 + (size_t)MPAD * NGATE;
    float gi = g0[o]          + g1[o]          + biasv[o];
    float gf = g0[H2 + o]     + g1[H2 + o]     + biasv[H2 + o];
    float gt = g0[2 * H2 + o] + g1[2 * H2 + o] + biasv[2 * H2 + o];
    float go = g0[3 * H2 + o] + g1[3 * H2 + o] + biasv[3 * H2 + o];
    float iv = 1.f / (1.f + expf(-gi));
    float fv = 1.f / (1.f + expf(-gf));
    float tv = tanhf(gt);
    float ov = 1.f / (1.f + expf(-go));
    float c = fv * c0[(size_t)n * H2 + o] + iv * tv;
    float h = ov * tanhf(c);
    out[N_REAL + (size_t)n * H2 + o] = h;

    float r = fmaxf(h, 0.f) * fc_w[o];
#pragma unroll
    for (int s = 32; s; s >>= 1) r += __shfl_down(r, s);
    if ((o & 63) == 0) red[o >> 6] = r;
    __syncthreads();
    if (o == 0 && n < N_REAL) out[n] = red[0] + red[1] + fc_b[0];
}

extern "C" void kernel_launch(void* const* d_in, const int* in_sizes, int n_in,
                              void* d_out, int out_size, void* d_ws, size_t ws_size,
                              hipStream_t stream) {
    const float* x     = (const float*)d_in[0];
    const int*   ei    = (const int*)d_in[1];
    const float* ew    = (const float*)d_in[2];
    const float* h0    = (const float*)d_in[3];
    const float* c0    = (const float*)d_in[4];
    const float* fc0_w = (const float*)d_in[5];
    const float* fc0_b = (const float*)d_in[6];
    const float* Wx    = (const float*)d_in[7];
    const float* bg    = (const float*)d_in[8];
    const float* cw0   = (const float*)d_in[9];
    const float* cw1   = (const float*)d_in[10];
    const float* cb    = (const float*)d_in[11];
    const float* fc_w  = (const float*)d_in[12];
    const float* fc_b  = (const float*)d_in[13];
    float* out = (float*)d_out;

    float* P      = (float*)d_ws;                       // 16*3072*256 f32 = 50.3 MB
    float* gates  = P + (size_t)SPLITK * MPAD * H1;     // 2*3072*512 f32
    float* biasv  = gates + 2 * (size_t)MPAD * NGATE;   // 512
    float* dinv   = biasv + NGATE;                      // 3072
    int*   offs   = (int*)(dinv + 3072);                // 3072
    int*   cnt_p  = offs + 3072;                        // 8*3072
    int*   eid    = cnt_p + NHB * 3072;                 // NE
    float* deg_p  = (float*)(eid + NE);                 // 8*3072
    _Float16* U16 = (_Float16*)(((uintptr_t)(deg_p + NHB * 3072) + 255) & ~(uintptr_t)255); // 3072*512
    _Float16* Wcp = U16 + (size_t)MPAD * UDIM;          // 512*512
    _Float16* wTp = Wcp + (size_t)UDIM * NGATE;         // 256*8192

    prep_kernel<<<3456, 256, 0, stream>>>(fc0_w, Wx, cw0, cw1, bg, cb, h0, wTp, Wcp, biasv, U16);
    g1hist_kernel<<<NHB + (MPAD / 64) * SPLITK, 256, 0, stream>>>(x, wTp, ei, ew, P, cnt_p, deg_p);
    scanz_kernel<<<385, 256, 0, stream>>>(cnt_p, deg_p, offs, dinv, P, fc0_b, U16);
    scatz_kernel<<<NHB + 384, 256, 0, stream>>>(ei, offs, cnt_p, eid, P, fc0_b, U16);
    g2gather_kernel<<<96 + NPAD, 256, 0, stream>>>(U16, U16, Wcp, gates, ei, ew, h0, dinv, offs, eid);
    gemm2b_kernel<<<96, 256, 0, stream>>>(U16, Wcp, gates);
    lstm_kernel<<<NPAD, 128, 0, stream>>>(gates, c0, biasv, fc_w, fc_b, out);
}

// Round 3
// 242.937 us; speedup vs baseline: 1.3819x; 1.3819x over previous
//
#include <hip/hip_runtime.h>
#include <math.h>

#define N_REAL 2800
#define NPAD   3000
#define F_IN   8192
#define H1     256
#define H2     128
#define NE     179200
#define UDIM   512
#define NGATE  512
#define MPAD   3072
#define SPLITK 16
#define KCH    (F_IN / SPLITK)   // 512
#define NHB    64                // privatized hist/scatter blocks
#define EPB    (NE / NHB)        // 2800 edges per hist/scatter block

typedef _Float16 half8_t __attribute__((ext_vector_type(8)));
typedef _Float16 half4_t __attribute__((ext_vector_type(4)));
typedef float    floatx4 __attribute__((ext_vector_type(4)));

__device__ __forceinline__ void async_g2l_16(const _Float16* g, _Float16* l) {
    __builtin_amdgcn_global_load_lds(
        (const __attribute__((address_space(1))) unsigned int*)g,
        (__attribute__((address_space(3))) unsigned int*)l, 16, 0, 0);
}

// ---------------- prep: hist (64 LDS blocks) | fc0_w -> wTp | Wcp + biasv | h0 -> U16 ----------
__global__ __launch_bounds__(256)
void prep_kernel(const float* __restrict__ w, const float* __restrict__ Wx,
                 const float* __restrict__ cw0, const float* __restrict__ cw1,
                 const float* __restrict__ bg, const float* __restrict__ cb,
                 const float* __restrict__ h0, const int* __restrict__ ei,
                 const float* __restrict__ ew,
                 _Float16* __restrict__ wTp, _Float16* __restrict__ Wcp,
                 float* __restrict__ biasv, _Float16* __restrict__ U16,
                 float* __restrict__ deg, int* __restrict__ counts,
                 int* __restrict__ cnt_pT) {
    __shared__ __align__(16) char pmem[24576];
    int b = blockIdx.x;
    int t = threadIdx.x;
    if (b < NHB) {
        // LDS-privatized histogram; merge via coalesced (different-address) global atomics.
        float* sdeg = (float*)pmem;            // 3072 f32
        int*   scnt = (int*)(pmem + 12288);    // 3072 int
        for (int i = t; i < 3072; i += 256) { sdeg[i] = 0.f; scnt[i] = 0; }
        __syncthreads();
        int e0 = b * EPB;
        for (int i = t; i < EPB; i += 256) {
            int e = e0 + i;
            atomicAdd(&sdeg[ei[e]], ew[e]);
            atomicAdd(&scnt[ei[NE + e]], 1);
        }
        __syncthreads();
        for (int i = t; i < 3072; i += 256) {
            atomicAdd(&deg[i], sdeg[i]);
            atomicAdd(&counts[i], scnt[i]);
            cnt_pT[i * NHB + b] = scnt[i];     // transposed partial for scatter bases
        }
    } else if (b < 2112) {
        float (*tile)[33] = (float(*)[33])pmem;
        int bb = b - NHB;
        int k0 = (bb & 255) * 32;
        int n0 = (bb >> 8) * 32;
        int tx = t & 31, ty = t >> 5; // 32 x 8
#pragma unroll
        for (int r = 0; r < 4; r++)
            tile[ty + r * 8][tx] = w[(size_t)(k0 + ty + r * 8) * H1 + n0 + tx];
        __syncthreads();
        if (t < 128) {
            int u_l = t >> 5;
            int n_l = t & 31;
            half8_t h;
#pragma unroll
            for (int j = 0; j < 8; j++) h[j] = (_Float16)tile[u_l * 8 + j][n_l];
            *(half8_t*)&wTp[(((size_t)(k0 >> 3) + u_l) * H1 + n0 + n_l) * 8] = h;
        }
    } else if (b < 3136) {
        int idx = (b - 2112) * 256 + t;
        if (idx < UDIM * NGATE) {
            int col = idx >> 9;
            int f   = idx & 511;
            int g = col >> 7, o = col & 127;
            float v;
            if (f < H1)            v = Wx[((size_t)g * H1 + f) * H2 + o];
            else if (f < H1 + H2)  v = cw0[((size_t)g * H2 + (f - H1)) * H2 + o];
            else                   v = cw1[((size_t)g * H2 + (f - H1 - H2)) * H2 + o];
            Wcp[(((size_t)(f >> 3)) * NGATE + col) * 8 + (f & 7)] = (_Float16)v;
            if (f == 0) biasv[col] = bg[col] + cb[col];
        }
    } else {
        int q = (b - 3136) * 256 + t;   // 0..98303
        int m = q >> 5;
        int o4 = (q & 31) * 4;
        half4_t h = {};
        if (m < NPAD) {
            float4 v = *(const float4*)&h0[(size_t)m * H2 + o4];
            h[0] = (_Float16)v.x; h[1] = (_Float16)v.y; h[2] = (_Float16)v.z; h[3] = (_Float16)v.w;
        }
        *(half4_t*)&U16[(size_t)m * UDIM + H1 + o4] = h;
    }
}

// ---------------- GEMM1 (R0 form): P[sk] = x(f32->f16) @ W, tile 64x256 ------------------------
__global__ __launch_bounds__(256, 3)
void gemm1_fused(const float* __restrict__ x, const _Float16* __restrict__ wTp,
                 float* __restrict__ P) {
    __shared__ __align__(16) _Float16 As[8][64][8];   // 8 KB
    __shared__ __align__(16) _Float16 Bs[8][256][8];  // 32 KB
    const int t = threadIdx.x;
    const int wave = t >> 6, lane = t & 63;
    const int l16 = lane & 15, u4 = lane >> 4;
    const int m0 = blockIdx.x * 64;
    const int kbase = blockIdx.y * KCH;

    const int arow = t >> 2;      // 0..63
    const int aseg = t & 3;       // 0..3 (16 f32 each)
    const bool avalid = (m0 + arow) < N_REAL;
    const float* agp = x + (size_t)(m0 + arow) * F_IN + kbase + aseg * 16;

    floatx4 acc[4][4] = {};

    float4 a0 = make_float4(0.f, 0.f, 0.f, 0.f), a1 = a0, a2 = a0, a3 = a0;
    if (avalid) {
        a0 = *(const float4*)(agp + 0);
        a1 = *(const float4*)(agp + 4);
        a2 = *(const float4*)(agp + 8);
        a3 = *(const float4*)(agp + 12);
    }

    for (int kk = 0; kk < KCH; kk += 64) {
        const _Float16* bbase = wTp + ((size_t)((kbase + kk) >> 3)) * (H1 * 8);
#pragma unroll
        for (int q = 0; q < 2; q++) {
            int u = wave * 2 + q;
#pragma unroll
            for (int rg = 0; rg < 4; rg++)
                async_g2l_16(bbase + ((size_t)u * H1 + rg * 64 + lane) * 8,
                             &Bs[u][rg * 64 + lane][0]);
        }
        half8_t hlo, hhi;
        hlo[0] = (_Float16)a0.x; hlo[1] = (_Float16)a0.y; hlo[2] = (_Float16)a0.z; hlo[3] = (_Float16)a0.w;
        hlo[4] = (_Float16)a1.x; hlo[5] = (_Float16)a1.y; hlo[6] = (_Float16)a1.z; hlo[7] = (_Float16)a1.w;
        hhi[0] = (_Float16)a2.x; hhi[1] = (_Float16)a2.y; hhi[2] = (_Float16)a2.z; hhi[3] = (_Float16)a2.w;
        hhi[4] = (_Float16)a3.x; hhi[5] = (_Float16)a3.y; hhi[6] = (_Float16)a3.z; hhi[7] = (_Float16)a3.w;
        *(half8_t*)&As[aseg * 2][arow][0]     = hlo;
        *(half8_t*)&As[aseg * 2 + 1][arow][0] = hhi;
        __syncthreads();
        if (kk + 64 < KCH && avalid) {
            a0 = *(const float4*)(agp + kk + 64);
            a1 = *(const float4*)(agp + kk + 68);
            a2 = *(const float4*)(agp + kk + 72);
            a3 = *(const float4*)(agp + kk + 76);
        }
#pragma unroll
        for (int ks = 0; ks < 2; ks++) {
            half8_t a[4], bfr[4];
#pragma unroll
            for (int i = 0; i < 4; i++) a[i] = *(const half8_t*)&As[ks * 4 + u4][i * 16 + l16][0];
#pragma unroll
            for (int j = 0; j < 4; j++) bfr[j] = *(const half8_t*)&Bs[ks * 4 + u4][wave * 64 + j * 16 + l16][0];
#pragma unroll
            for (int i = 0; i < 4; i++)
#pragma unroll
                for (int j = 0; j < 4; j++)
                    acc[i][j] = __builtin_amdgcn_mfma_f32_16x16x32_f16(a[i], bfr[j], acc[i][j], 0, 0, 0);
        }
        __syncthreads();
    }

    float* Pb = P + ((size_t)blockIdx.y * MPAD + m0) * H1;
#pragma unroll
    for (int i = 0; i < 4; i++)
#pragma unroll
        for (int j = 0; j < 4; j++) {
            int n = wave * 64 + j * 16 + l16;
#pragma unroll
            for (int r = 0; r < 4; r++)
                Pb[(size_t)(i * 16 + u4 * 4 + r) * H1 + n] = acc[i][j][r];
        }
}

// ---------------- shared zreduce body: P slices -> relu -> U16 z slice (256 thr) ---------------
__device__ __forceinline__ void zreduce_body(int zb, int t, const float* __restrict__ P,
                                             const float* __restrict__ fc0_b,
                                             _Float16* __restrict__ U16) {
    int q = zb * 256 + t;
    int m = q >> 6;
    int n4 = (q & 63) * 4;
    float s0 = 0.f, s1 = 0.f, s2 = 0.f, s3 = 0.f;
#pragma unroll
    for (int sk = 0; sk < SPLITK; sk++) {
        float4 p = *(const float4*)&P[((size_t)sk * MPAD + m) * H1 + n4];
        s0 += p.x; s1 += p.y; s2 += p.z; s3 += p.w;
    }
    float4 bb = *(const float4*)&fc0_b[n4];
    half4_t h;
    h[0] = (_Float16)fmaxf(s0 + bb.x, 0.f);
    h[1] = (_Float16)fmaxf(s1 + bb.y, 0.f);
    h[2] = (_Float16)fmaxf(s2 + bb.z, 0.f);
    h[3] = (_Float16)fmaxf(s3 + bb.w, 0.f);
    *(half4_t*)&U16[(size_t)m * UDIM + n4] = h;
}

// -------- scanz: b0 prefix+dinv | b1..12 per-(col,block) base prefix | b13+ zreduce -------------
__global__ __launch_bounds__(256)
void scanz_kernel(const int* __restrict__ counts, const float* __restrict__ deg,
                  int* __restrict__ offsets, float* __restrict__ dinv,
                  const int* __restrict__ cnt_pT, int* __restrict__ base_rel,
                  const float* __restrict__ P, const float* __restrict__ fc0_b,
                  _Float16* __restrict__ U16) {
    int b = blockIdx.x;
    int t = threadIdx.x;
    if (b == 0) {
        __shared__ int wt[4];
        int i0 = t * 12;
        int v[12];
        int s = 0;
#pragma unroll
        for (int j = 0; j < 12; j++) { v[j] = counts[i0 + j]; s += v[j]; }
        int incl = s;
#pragma unroll
        for (int d = 1; d < 64; d <<= 1) {
            int n = __shfl_up(incl, d);
            if ((t & 63) >= d) incl += n;
        }
        if ((t & 63) == 63) wt[t >> 6] = incl;
        __syncthreads();
        int wbase = 0;
#pragma unroll
        for (int w = 0; w < 4; w++) wbase += (w < (t >> 6)) ? wt[w] : 0;
        int run = wbase + incl - s;
#pragma unroll
        for (int j = 0; j < 12; j++) { offsets[i0 + j] = run; run += v[j]; }
        for (int i = t; i < NPAD; i += 256) {
            float d = deg[i];
            dinv[i] = (d > 0.f) ? rsqrtf(d) : 0.f;
        }
    } else if (b <= 12) {
        // exclusive prefix over the 64 per-block counts for each column (no offsets dep)
        int j = (b - 1) * 256 + t;            // 0..3071
        const int* src = cnt_pT + (size_t)j * NHB;
        int* dst = base_rel + (size_t)j * NHB;
        int run = 0;
#pragma unroll
        for (int bb = 0; bb < NHB; bb++) { dst[bb] = run; run += src[bb]; }
    } else {
        zreduce_body(b - 13, t, P, fc0_b, U16);      // zb 0..383
    }
}

// -------- scatz: 64 LDS-cursor scatter blocks (no global atomics) | zreduce second half ---------
__global__ __launch_bounds__(256)
void scatz_kernel(const int* __restrict__ ei, const int* __restrict__ offsets,
                  const int* __restrict__ base_rel, int* __restrict__ eid,
                  const float* __restrict__ P, const float* __restrict__ fc0_b,
                  _Float16* __restrict__ U16) {
    int b = blockIdx.x;
    int t = threadIdx.x;
    if (b < NHB) {
        __shared__ int sb[3072];
        for (int j = t; j < 3072; j += 256)
            sb[j] = offsets[j] + base_rel[(size_t)j * NHB + b];
        __syncthreads();
        int e0 = b * EPB;
        for (int i = t; i < EPB; i += 256) {
            int e = e0 + i;
            int c = ei[NE + e];
            int p = atomicAdd(&sb[c], 1);
            eid[p] = e;
        }
    } else {
        zreduce_body(384 + (b - NHB), t, P, fc0_b, U16);  // zb 384..767
    }
}

// ---------------- T1 gather (CSR, ILP-8, 128 thr) -> U16 T1 slice ------------------------------
__global__ __launch_bounds__(128)
void gather_kernel(const int* __restrict__ ei, const float* __restrict__ ew,
                   const float* __restrict__ h0, const float* __restrict__ dinv,
                   const int* __restrict__ offsets, const int* __restrict__ eid,
                   _Float16* __restrict__ U16) {
    __shared__ int   sr[128];
    __shared__ float sw[128];
    int n = blockIdx.x;
    int t = threadIdx.x;
    int beg = offsets[n], end = offsets[n + 1];
    float dc = dinv[n];
    float acc = 0.f;
    for (int base = beg; base < end; base += 128) {
        int j = base + t;
        if (j < end) {
            int e = eid[j];
            int r = ei[e];
            sr[t] = r;
            sw[t] = -dinv[r] * ew[e];
        }
        __syncthreads();
        int cnt = min(128, end - base);
        int k = 0;
        for (; k + 8 <= cnt; k += 8) {
            int   r0 = sr[k],   r1 = sr[k+1], r2 = sr[k+2], r3 = sr[k+3];
            int   r4 = sr[k+4], r5 = sr[k+5], r6 = sr[k+6], r7 = sr[k+7];
            float w0 = sw[k],   w1 = sw[k+1], w2 = sw[k+2], w3 = sw[k+3];
            float w4 = sw[k+4], w5 = sw[k+5], w6 = sw[k+6], w7 = sw[k+7];
            float v0 = h0[(size_t)r0 * H2 + t];
            float v1 = h0[(size_t)r1 * H2 + t];
            float v2 = h0[(size_t)r2 * H2 + t];
            float v3 = h0[(size_t)r3 * H2 + t];
            float v4 = h0[(size_t)r4 * H2 + t];
            float v5 = h0[(size_t)r5 * H2 + t];
            float v6 = h0[(size_t)r6 * H2 + t];
            float v7 = h0[(size_t)r7 * H2 + t];
            acc += w0 * v0 + w1 * v1 + w2 * v2 + w3 * v3
                 + w4 * v4 + w5 * v5 + w6 * v6 + w7 * v7;
        }
        for (; k < cnt; k++)
            acc += sw[k] * h0[(size_t)sr[k] * H2 + t];
        __syncthreads();
    }
    U16[(size_t)n * UDIM + H1 + H2 + t] = (_Float16)(acc * dc);
}

// ---------------- GEMM2 (MFMA f16, split-K=2): gatesP[z] = U16 @ W slice ------------------------
__global__ __launch_bounds__(256, 3)
void gemm2_mfma(const _Float16* __restrict__ U16, const _Float16* __restrict__ Wcp,
                float* __restrict__ gatesP) {
    __shared__ __align__(16) _Float16 As[8][64][8];
    __shared__ __align__(16) _Float16 Bs[8][256][8];
    const int t = threadIdx.x;
    const int wave = t >> 6, lane = t & 63;
    const int l16 = lane & 15, u4 = lane >> 4;
    const int n0 = blockIdx.x * 256;
    const int m0 = blockIdx.y * 64;
    const int kz = blockIdx.z * 256;

    floatx4 acc[4][4] = {};

    for (int kk = kz; kk < kz + 256; kk += 64) {
        const _Float16* bbase = Wcp + ((size_t)(kk >> 3)) * (NGATE * 8);
#pragma unroll
        for (int q = 0; q < 2; q++) {
            int u = wave * 2 + q;
            async_g2l_16(U16 + (size_t)(m0 + lane) * UDIM + kk + u * 8, &As[u][lane][0]);
#pragma unroll
            for (int rg = 0; rg < 4; rg++)
                async_g2l_16(bbase + ((size_t)u * NGATE + n0 + rg * 64 + lane) * 8,
                             &Bs[u][rg * 64 + lane][0]);
        }
        __syncthreads();
#pragma unroll
        for (int ks = 0; ks < 2; ks++) {
            half8_t a[4], bfr[4];
#pragma unroll
            for (int i = 0; i < 4; i++) a[i] = *(const half8_t*)&As[ks * 4 + u4][i * 16 + l16][0];
#pragma unroll
            for (int j = 0; j < 4; j++) bfr[j] = *(const half8_t*)&Bs[ks * 4 + u4][wave * 64 + j * 16 + l16][0];
#pragma unroll
            for (int i = 0; i < 4; i++)
#pragma unroll
                for (int j = 0; j < 4; j++)
                    acc[i][j] = __builtin_amdgcn_mfma_f32_16x16x32_f16(a[i], bfr[j], acc[i][j], 0, 0, 0);
        }
        __syncthreads();
    }

    float* g = gatesP + (size_t)blockIdx.z * MPAD * NGATE;
#pragma unroll
    for (int i = 0; i < 4; i++)
#pragma unroll
        for (int j = 0; j < 4; j++) {
            int n = n0 + wave * 64 + j * 16 + l16;
#pragma unroll
            for (int r = 0; r < 4; r++)
                g[(size_t)(m0 + i * 16 + u4 * 4 + r) * NGATE + n] = acc[i][j][r];
        }
}

// ---------------- LSTM elementwise + bias + output projection ----------------------------------
__global__ __launch_bounds__(128)
void lstm_kernel(const float* __restrict__ gates, const float* __restrict__ c0,
                 const float* __restrict__ biasv, const float* __restrict__ fc_w,
                 const float* __restrict__ fc_b, float* __restrict__ out) {
    __shared__ float red[2];
    int n = blockIdx.x;
    int o = threadIdx.x;
    const float* g0 = gates + (size_t)n * NGATE;
    const float* g1 = g0 + (size_t)MPAD * NGATE;
    float gi = g0[o]          + g1[o]          + biasv[o];
    float gf = g0[H2 + o]     + g1[H2 + o]     + biasv[H2 + o];
    float gt = g0[2 * H2 + o] + g1[2 * H2 + o] + biasv[2 * H2 + o];
    float go = g0[3 * H2 + o] + g1[3 * H2 + o] + biasv[3 * H2 + o];
    float iv = 1.f / (1.f + expf(-gi));
    float fv = 1.f / (1.f + expf(-gf));
    float tv = tanhf(gt);
    float ov = 1.f / (1.f + expf(-go));
    float c = fv * c0[(size_t)n * H2 + o] + iv * tv;
    float h = ov * tanhf(c);
    out[N_REAL + (size_t)n * H2 + o] = h;

    float r = fmaxf(h, 0.f) * fc_w[o];
#pragma unroll
    for (int s = 32; s; s >>= 1) r += __shfl_down(r, s);
    if ((o & 63) == 0) red[o >> 6] = r;
    __syncthreads();
    if (o == 0 && n < N_REAL) out[n] = red[0] + red[1] + fc_b[0];
}

extern "C" void kernel_launch(void* const* d_in, const int* in_sizes, int n_in,
                              void* d_out, int out_size, void* d_ws, size_t ws_size,
                              hipStream_t stream) {
    const float* x     = (const float*)d_in[0];
    const int*   ei    = (const int*)d_in[1];
    const float* ew    = (const float*)d_in[2];
    const float* h0    = (const float*)d_in[3];
    const float* c0    = (const float*)d_in[4];
    const float* fc0_w = (const float*)d_in[5];
    const float* fc0_b = (const float*)d_in[6];
    const float* Wx    = (const float*)d_in[7];
    const float* bg    = (const float*)d_in[8];
    const float* cw0   = (const float*)d_in[9];
    const float* cw1   = (const float*)d_in[10];
    const float* cb    = (const float*)d_in[11];
    const float* fc_w  = (const float*)d_in[12];
    const float* fc_b  = (const float*)d_in[13];
    float* out = (float*)d_out;

    float* P        = (float*)d_ws;                       // 16*3072*256 f32 = 50.3 MB
    float* gates    = P + (size_t)SPLITK * MPAD * H1;     // 2*3072*512 f32
    float* biasv    = gates + 2 * (size_t)MPAD * NGATE;   // 512
    float* dinv     = biasv + NGATE;                      // 3072
    float* deg      = dinv + 3072;                        // 3072  (memset target, with counts)
    int*   counts   = (int*)(deg + 3072);                 // 3072
    int*   offs     = counts + 3072;                      // 3072
    int*   cnt_pT   = offs + 3072;                        // 3072*64
    int*   base_rel = cnt_pT + 3072 * NHB;                // 3072*64
    int*   eid      = base_rel + 3072 * NHB;              // NE
    _Float16* U16 = (_Float16*)(((uintptr_t)(eid + NE) + 255) & ~(uintptr_t)255); // 3072*512
    _Float16* Wcp = U16 + (size_t)MPAD * UDIM;            // 512*512
    _Float16* wTp = Wcp + (size_t)UDIM * NGATE;           // 256*8192

    hipMemsetAsync(deg, 0, 2 * 3072 * sizeof(float), stream);   // deg + counts
    prep_kernel<<<3520, 256, 0, stream>>>(fc0_w, Wx, cw0, cw1, bg, cb, h0, ei, ew,
                                          wTp, Wcp, biasv, U16, deg, counts, cnt_pT);
    gemm1_fused<<<dim3(MPAD / 64, SPLITK), 256, 0, stream>>>(x, wTp, P);
    scanz_kernel<<<397, 256, 0, stream>>>(counts, deg, offs, dinv, cnt_pT, base_rel, P, fc0_b, U16);
    scatz_kernel<<<NHB + 384, 256, 0, stream>>>(ei, offs, base_rel, eid, P, fc0_b, U16);
    gather_kernel<<<NPAD, 128, 0, stream>>>(ei, ew, h0, dinv, offs, eid, U16);
    gemm2_mfma<<<dim3(NGATE / 256, MPAD / 64, 2), 256, 0, stream>>>(U16, Wcp, gates);
    lstm_kernel<<<NPAD, 128, 0, stream>>>(gates, c0, biasv, fc_w, fc_b, out);
}